// Round 8
// baseline (272.536 us; speedup 1.0000x reference)
//
#include <hip/hip_runtime.h>
#include <hip/hip_bf16.h>
#include <hip/hip_cooperative_groups.h>

namespace cg = cooperative_groups;

#define N_PTS 20000
#define NSAMP 32
#define CIN 64
#define COUT 128
#define M_ROWS (N_PTS * NSAMP)   // 640000 rows
#define TILES (M_ROWS / 64)      // 10000 64-row tiles
#define BN_EPS 1e-5f

// cooperative stats kernel geometry
#define CBLOCKS 500              // x4 waves = 2000 waves -> exactly 5 tiles/wave
#define CWAVES (CBLOCKS * 4)

// fallback (R7-proven) geometry
#define K1_BLOCKS 1250
#define K1_WAVES (K1_BLOCKS * 4) // 5000 -> exactly 2 tiles per wave
#define SP_CHUNKS 25
#define SP_DEPTH 50
#define CP_CHUNKS 50
#define CP_DEPTH 100

typedef __attribute__((ext_vector_type(8))) short short8v;
typedef __attribute__((ext_vector_type(4))) float f32x4;

// float -> bf16 bits, round-to-nearest-even
__device__ inline short bf16_of(float f) {
    unsigned u = __float_as_uint(f);
    u = (u + 0x7FFFu + ((u >> 16) & 1u)) >> 16;
    return (short)u;
}

// ===========================================================================
// Cooperative stats kernel: Phase A (Gram+colsum partials, R2-proven loop)
// -> grid.sync -> Phase B1 (depth-500 tree reduce Sp->S) -> grid.sync ->
// Phase B2 (BN scale/shift).  VGPR capped at 128 so 4 blocks/CU are
// guaranteed co-resident (capacity 1024 blocks >> 500 launched).
// ===========================================================================
__global__ __launch_bounds__(256, 4) void coop_stats(
    const float* __restrict__ F, const float* __restrict__ W,
    const float* __restrict__ gamma, const float* __restrict__ beta,
    float* __restrict__ scale, float* __restrict__ shift,
    float* __restrict__ S, float* __restrict__ Sp, float* __restrict__ Cp) {
    cg::grid_group grid = cg::this_grid();

    const int tid = threadIdx.x;
    const int wid = tid >> 6;
    const int lane = tid & 63;
    const int g = lane >> 4;
    const int i = lane & 15;
    const int bid = blockIdx.x;
    const int gw = bid * 4 + wid;

    __shared__ float sS[4096];
    __shared__ float sC[4][64];
    __shared__ float sw[64];

    // ---------------- Phase A: Gram + colsum partials ----------------
    {
        f32x4 acc[4][4];
#pragma unroll
        for (int a = 0; a < 4; ++a)
#pragma unroll
            for (int b = 0; b < 4; ++b)
                acc[a][b] = (f32x4){0.f, 0.f, 0.f, 0.f};
        float colp[4] = {0.f, 0.f, 0.f, 0.f};

        for (int tile = gw; tile < TILES; tile += CWAVES) {
            const float* fb0 = F + (size_t)tile * 4096 + g * 512 + i;
            const float* fb1 = fb0 + 2048;
            short8v frag[4][2];
#pragma unroll
            for (int jt = 0; jt < 4; ++jt) {
                float cs = 0.f;
#pragma unroll
                for (int kk = 0; kk < 2; ++kk) {
                    const float* p = kk ? fb1 : fb0;
                    short8v fr;
#pragma unroll
                    for (int r = 0; r < 8; ++r) {
                        float v = p[r * 64 + jt * 16];
                        cs += v;
                        fr[r] = bf16_of(v);
                    }
                    frag[jt][kk] = fr;
                }
                colp[jt] += cs;
            }
#pragma unroll
            for (int it = 0; it < 4; ++it)
#pragma unroll
                for (int jt = 0; jt < 4; ++jt) {
                    acc[it][jt] = __builtin_amdgcn_mfma_f32_16x16x32_bf16(
                        frag[it][0], frag[jt][0], acc[it][jt], 0, 0, 0);
                    acc[it][jt] = __builtin_amdgcn_mfma_f32_16x16x32_bf16(
                        frag[it][1], frag[jt][1], acc[it][jt], 0, 0, 0);
                }
        }

#pragma unroll
        for (int jt = 0; jt < 4; ++jt) {
            colp[jt] += __shfl_xor(colp[jt], 16);
            colp[jt] += __shfl_xor(colp[jt], 32);
        }
        if (lane < 16) {
#pragma unroll
            for (int jt = 0; jt < 4; ++jt)
                Cp[gw * 64 + jt * 16 + lane] = colp[jt];
        }

        for (int w = 0; w < 4; ++w) {
            if (wid == w) {
#pragma unroll
                for (int it = 0; it < 4; ++it)
#pragma unroll
                    for (int jt = 0; jt < 4; ++jt)
#pragma unroll
                        for (int r = 0; r < 4; ++r) {
                            // C/D layout: col = lane&15, row = (lane>>4)*4 + r
                            int idx = (it * 16 + g * 4 + r) * 64 + jt * 16 + i;
                            if (w == 0) sS[idx] = acc[it][jt][r];
                            else        sS[idx] += acc[it][jt][r];
                        }
            }
            __syncthreads();
        }
        float4* dst = (float4*)(Sp + (size_t)bid * 4096);
        const float4* src = (const float4*)sS;
#pragma unroll
        for (int q = 0; q < 4; ++q)
            dst[q * 256 + tid] = src[q * 256 + tid];
    }
    grid.sync();

    // ---------------- Phase B1: Sp depth-500 tree reduce ----------------
    {
        float s1 = 0.f;
        if (bid < 64) {
            const size_t base = (size_t)(wid * 125) * 4096 + bid * 64 + lane;
#pragma unroll 5
            for (int p = 0; p < 125; ++p) s1 += Sp[base + (size_t)p * 4096];
        }
        __syncthreads();  // sC free from phase A
        sC[wid][lane] = s1;
        __syncthreads();
        if (bid < 64 && tid < 64)
            S[bid * 64 + tid] =
                sC[0][tid] + sC[1][tid] + sC[2][tid] + sC[3][tid];
    }
    grid.sync();

    // ---------------- Phase B2: BN scale/shift per channel ----------------
    if (bid < COUT) {
        // parallel colsum: 4 wid-groups x 500 partials each
        float csp = 0.f;
        {
            const int base = wid * 500;
#pragma unroll 5
            for (int p = 0; p < 500; ++p) csp += Cp[(base + p) * 64 + lane];
        }
        __syncthreads();
        sC[wid][lane] = csp;
        if (tid < 64) sw[tid] = W[bid * 64 + tid];
        __syncthreads();
        if (tid < 64) {
            float w_t = sw[tid];
            float rowdot = 0.f;
#pragma unroll
            for (int j = 0; j < 64; ++j) rowdot += S[tid * 64 + j] * sw[j];
            float cs = sC[0][tid] + sC[1][tid] + sC[2][tid] + sC[3][tid];
            float pp = w_t * rowdot;
            float mup = w_t * cs;
            for (int k = 1; k <= 32; k <<= 1) {
                pp += __shfl_xor(pp, k);
                mup += __shfl_xor(mup, k);
            }
            if (tid == 0) {
                const float invM = 1.f / (float)M_ROWS;
                float mu = mup * invM;
                float ex2 = pp * invM;
                float var = ex2 - mu * mu;
                float rs = rsqrtf(var + BN_EPS);
                float sc = gamma[bid] * rs;
                scale[bid] = sc;
                shift[bid] = beta[bid] - mu * sc;
            }
        }
    }
}

// ===========================================================================
// Fallback path (exact R7 kernels, known-good 96 us) — used only if the
// cooperative launch is rejected by the runtime.
// ===========================================================================
__global__ __launch_bounds__(256) void k1_stats(const float* __restrict__ F,
                                                float* __restrict__ Sp,
                                                float* __restrict__ Cp) {
    const int tid = threadIdx.x;
    const int wid = tid >> 6;
    const int lane = tid & 63;
    const int g = lane >> 4;
    const int i = lane & 15;
    const int gw = blockIdx.x * 4 + wid;

    f32x4 acc[4][4];
#pragma unroll
    for (int a = 0; a < 4; ++a)
#pragma unroll
        for (int b = 0; b < 4; ++b)
            acc[a][b] = (f32x4){0.f, 0.f, 0.f, 0.f};
    float colp[4] = {0.f, 0.f, 0.f, 0.f};

    for (int tile = gw; tile < TILES; tile += K1_WAVES) {
        const float* fb0 = F + (size_t)tile * 4096 + g * 512 + i;
        const float* fb1 = fb0 + 2048;
        short8v frag[4][2];
#pragma unroll
        for (int jt = 0; jt < 4; ++jt) {
            float cs = 0.f;
#pragma unroll
            for (int kk = 0; kk < 2; ++kk) {
                const float* p = kk ? fb1 : fb0;
                short8v fr;
#pragma unroll
                for (int r = 0; r < 8; ++r) {
                    float v = p[r * 64 + jt * 16];
                    cs += v;
                    fr[r] = bf16_of(v);
                }
                frag[jt][kk] = fr;
            }
            colp[jt] += cs;
        }
#pragma unroll
        for (int it = 0; it < 4; ++it)
#pragma unroll
            for (int jt = 0; jt < 4; ++jt) {
                acc[it][jt] = __builtin_amdgcn_mfma_f32_16x16x32_bf16(
                    frag[it][0], frag[jt][0], acc[it][jt], 0, 0, 0);
                acc[it][jt] = __builtin_amdgcn_mfma_f32_16x16x32_bf16(
                    frag[it][1], frag[jt][1], acc[it][jt], 0, 0, 0);
            }
    }

#pragma unroll
    for (int jt = 0; jt < 4; ++jt) {
        colp[jt] += __shfl_xor(colp[jt], 16);
        colp[jt] += __shfl_xor(colp[jt], 32);
    }
    if (lane < 16) {
#pragma unroll
        for (int jt = 0; jt < 4; ++jt)
            Cp[gw * 64 + jt * 16 + lane] = colp[jt];
    }

    __shared__ float sS[4096];
    for (int w = 0; w < 4; ++w) {
        if (wid == w) {
#pragma unroll
            for (int it = 0; it < 4; ++it)
#pragma unroll
                for (int jt = 0; jt < 4; ++jt)
#pragma unroll
                    for (int r = 0; r < 4; ++r) {
                        int idx = (it * 16 + g * 4 + r) * 64 + jt * 16 + i;
                        if (w == 0) sS[idx] = acc[it][jt][r];
                        else        sS[idx] += acc[it][jt][r];
                    }
        }
        __syncthreads();
    }
    float4* dst = (float4*)(Sp + (size_t)blockIdx.x * 4096);
    const float4* src = (const float4*)sS;
#pragma unroll
    for (int q = 0; q < 4; ++q)
        dst[q * 256 + tid] = src[q * 256 + tid];
}

__global__ __launch_bounds__(256) void kRedA(const float* __restrict__ Sp,
                                             const float* __restrict__ Cp,
                                             float* __restrict__ Tp,
                                             float* __restrict__ Tcp) {
    int t = blockIdx.x * 256 + threadIdx.x;
    if (t < SP_CHUNKS * 4096) {
        int o = t & 4095;
        int c = t >> 12;
        float s = 0.f;
#pragma unroll 10
        for (int b = 0; b < SP_DEPTH; ++b)
            s += Sp[(size_t)(c * SP_DEPTH + b) * 4096 + o];
        Tp[t] = s;
    } else if (t < SP_CHUNKS * 4096 + CP_CHUNKS * 64) {
        int u = t - SP_CHUNKS * 4096;
        int col = u & 63;
        int c = u >> 6;
        float s = 0.f;
#pragma unroll 10
        for (int w = 0; w < CP_DEPTH; ++w)
            s += Cp[(c * CP_DEPTH + w) * 64 + col];
        Tcp[u] = s;
    }
}

__global__ __launch_bounds__(256) void kRedB(const float* __restrict__ Tp,
                                             const float* __restrict__ Tcp,
                                             float* __restrict__ S,
                                             float* __restrict__ colsum) {
    int t = blockIdx.x * 256 + threadIdx.x;
    if (t < 4096) {
        float s = 0.f;
#pragma unroll
        for (int c = 0; c < SP_CHUNKS; ++c) s += Tp[c * 4096 + t];
        S[t] = s;
    } else if (t < 4160) {
        int col = t - 4096;
        float s = 0.f;
#pragma unroll
        for (int c = 0; c < CP_CHUNKS; ++c) s += Tcp[c * 64 + col];
        colsum[col] = s;
    }
}

__global__ __launch_bounds__(64) void k1_scales(const float* __restrict__ S,
                                                const float* __restrict__ colsum,
                                                const float* __restrict__ W,
                                                const float* __restrict__ gamma,
                                                const float* __restrict__ beta,
                                                float* __restrict__ scale,
                                                float* __restrict__ shift) {
    int d = blockIdx.x;
    int tid = threadIdx.x;
    __shared__ float w[64];
    w[tid] = W[d * 64 + tid];
    __syncthreads();
    float wi = w[tid];
    float rowdot = 0.f;
#pragma unroll
    for (int j = 0; j < 64; ++j) rowdot += S[tid * 64 + j] * w[j];
    float p = wi * rowdot;
    float mup = wi * colsum[tid];
    for (int k = 1; k <= 32; k <<= 1) {
        p += __shfl_xor(p, k);
        mup += __shfl_xor(mup, k);
    }
    if (tid == 0) {
        const float invM = 1.f / (float)M_ROWS;
        float mu = mup * invM;
        float ex2 = p * invM;
        float var = ex2 - mu * mu;
        float rs = rsqrtf(var + BN_EPS);
        float sc = gamma[d] * rs;
        scale[d] = sc;
        shift[d] = beta[d] - mu * sc;
    }
}

// ---------------------------------------------------------------------------
// Kernel 2 (exact R2 structure, best-measured): fused GEMM (bf16 MFMA) +
// BN affine + ReLU + geo-weighted masked mean-pool.  One wave per 4 points.
// ---------------------------------------------------------------------------
__global__ __launch_bounds__(256) void k2_main(const float* __restrict__ F,
                                               const float* __restrict__ coords,
                                               const float* __restrict__ centers,
                                               const int* __restrict__ mask,
                                               const float* __restrict__ W,
                                               const float* __restrict__ scale,
                                               const float* __restrict__ shift,
                                               float* __restrict__ out) {
    const int tid = threadIdx.x;
    const int wid = tid >> 6;
    const int lane = tid & 63;
    const int g = lane >> 4;
    const int i = lane & 15;
    const int n_base = (blockIdx.x * 4 + wid) * 4;

    short8v b[8][2];
#pragma unroll
    for (int t = 0; t < 8; ++t)
#pragma unroll
        for (int kk = 0; kk < 2; ++kk) {
            const float* wp = W + (t * 16 + i) * 64 + kk * 32 + g * 8;
            short8v fr;
#pragma unroll
            for (int r = 0; r < 8; ++r) fr[r] = bf16_of(wp[r]);
            b[t][kk] = fr;
        }
    float sc[8], sh[8];
#pragma unroll
    for (int t = 0; t < 8; ++t) {
        sc[t] = scale[t * 16 + i];
        sh[t] = shift[t * 16 + i];
    }

    __shared__ float geoM[4][32][4];
    const f32x4 Z = {0.f, 0.f, 0.f, 0.f};

    for (int it = 0; it < 4; ++it) {
        const int n = n_base + it;

        short8v a[2][2];
#pragma unroll
        for (int mt = 0; mt < 2; ++mt)
#pragma unroll
            for (int kk = 0; kk < 2; ++kk) {
                const float* fp =
                    F + ((size_t)n * NSAMP + mt * 16 + i) * 64 + kk * 32 + g * 8;
                short8v fr;
#pragma unroll
                for (int r = 0; r < 8; ++r) fr[r] = bf16_of(fp[r]);
                a[mt][kk] = fr;
            }

        float m = 0.f;
        if (lane < 32) {
            const int s = lane;
            const float* cp = coords + ((size_t)n * NSAMP + s) * 3;
            float r0 = cp[0] - centers[n * 4 + 1];
            float r1 = cp[1] - centers[n * 4 + 2];
            float r2 = cp[2] - centers[n * 4 + 3];
            float dist = r0 * r0 + r1 * r1 + r2 * r2;
            m = (float)mask[n * NSAMP + s];
            float4 gm = make_float4(r0 * 10.f * m, r1 * 10.f * m,
                                    r2 * 5.f * m, dist * (1.f / 0.06f) * m);
            *(float4*)&geoM[wid][s][0] = gm;
        }
        float den = m;
        for (int k = 1; k <= 32; k <<= 1) den += __shfl_xor(den, k);
        float inv_den = 1.f / fmaxf(den, 1.f);

        __builtin_amdgcn_sched_barrier(0x7F);

        float gv[2][4];
        const int j0 = i & 3;
#pragma unroll
        for (int mt = 0; mt < 2; ++mt)
#pragma unroll
            for (int r = 0; r < 4; ++r)
                gv[mt][r] = geoM[wid][mt * 16 + g * 4 + r][j0];

#pragma unroll
        for (int t = 0; t < 8; ++t) {
            float nump = 0.f;
#pragma unroll
            for (int mt = 0; mt < 2; ++mt) {
                f32x4 acc = __builtin_amdgcn_mfma_f32_16x16x32_bf16(
                    a[mt][0], b[t][0], Z, 0, 0, 0);
                acc = __builtin_amdgcn_mfma_f32_16x16x32_bf16(
                    a[mt][1], b[t][1], acc, 0, 0, 0);
#pragma unroll
                for (int r = 0; r < 4; ++r) {
                    float v = fmaf(acc[r], sc[t], sh[t]);
                    v = fmaxf(v, 0.f);
                    nump = fmaf(v, gv[mt][r], nump);
                }
            }
            nump += __shfl_xor(nump, 16);
            nump += __shfl_xor(nump, 32);
            if (lane < 16)
                out[(size_t)n * COUT + t * 16 + lane] = nump * inv_den;
        }
    }
}

// ---------------------------------------------------------------------------
extern "C" void kernel_launch(void* const* d_in, const int* in_sizes, int n_in,
                              void* d_out, int out_size, void* d_ws, size_t ws_size,
                              hipStream_t stream) {
    const float* F = (const float*)d_in[0];
    const float* coords = (const float*)d_in[1];
    const float* centers = (const float*)d_in[2];
    const int* mask = (const int*)d_in[3];
    const float* W = (const float*)d_in[4];
    const float* gamma = (const float*)d_in[5];
    const float* beta = (const float*)d_in[6];
    float* out = (float*)d_out;

    float* wsf = (float*)d_ws;
    float* scale = wsf;                           // 128
    float* shift = wsf + 128;                     // 128
    float* S = wsf + 256;                         // 4096
    float* colsum = wsf + 4352;                   // 64
    float* Tp = wsf + 4416;                       // 102400
    float* Tcp = Tp + SP_CHUNKS * 4096;           // 3200
    float* SpC = Tcp + CP_CHUNKS * 64;            // coop: 500*4096
    float* CpC = SpC + (size_t)CBLOCKS * 4096;    // coop: 2000*64
    float* SpF = CpC + (size_t)CWAVES * 64;       // fallback: 1250*4096
    float* CpF = SpF + (size_t)K1_BLOCKS * 4096;  // fallback: 5000*64

    const float* Fc = F; const float* Wc = W;
    const float* gc = gamma; const float* bc = beta;
    float* scc = scale; float* shc = shift;
    float* Sc = S; float* Spc = SpC; float* Cpc = CpC;
    void* kargs[] = {(void*)&Fc,  (void*)&Wc,  (void*)&gc, (void*)&bc,
                     (void*)&scc, (void*)&shc, (void*)&Sc, (void*)&Spc,
                     (void*)&Cpc};
    hipError_t err = hipLaunchCooperativeKernel(
        (const void*)coop_stats, dim3(CBLOCKS), dim3(256), kargs, 0, stream);

    if (err != hipSuccess) {
        // fallback: proven 5-kernel chain (R7)
        k1_stats<<<K1_BLOCKS, 256, 0, stream>>>(F, SpF, CpF);
        kRedA<<<413, 256, 0, stream>>>(SpF, CpF, Tp, Tcp);
        kRedB<<<17, 256, 0, stream>>>(Tp, Tcp, S, colsum);
        k1_scales<<<COUT, 64, 0, stream>>>(S, colsum, W, gamma, beta, scale,
                                           shift);
    }
    k2_main<<<1250, 256, 0, stream>>>(F, coords, centers, mask, W, scale,
                                      shift, out);
}

// Round 9
// 101.110 us; speedup vs baseline: 2.6954x; 2.6954x over previous
//
#include <hip/hip_runtime.h>
#include <hip/hip_bf16.h>

#define N_PTS 20000
#define NSAMP 32
#define CIN 64
#define COUT 128
#define M_ROWS (N_PTS * NSAMP)   // 640000 rows
#define TILES (M_ROWS / 64)      // 10000 64-row tiles
#define K1_BLOCKS 1250
#define K1_WAVES (K1_BLOCKS * 4) // 5000 -> exactly 2 tiles per wave
#define SP_CHUNKS 25
#define SP_DEPTH 50              // 25*50 = 1250 block partials
#define CP_CHUNKS 50
#define CP_DEPTH 100             // 50*100 = 5000 wave partials
#define BN_EPS 1e-5f

typedef __attribute__((ext_vector_type(8))) short short8v;
typedef __attribute__((ext_vector_type(4))) float f32x4;

// float -> bf16 bits, round-to-nearest-even
__device__ inline short bf16_of(float f) {
    unsigned u = __float_as_uint(f);
    u = (u + 0x7FFFu + ((u >> 16) & 1u)) >> 16;
    return (short)u;
}

// global -> LDS DMA, 16 B per lane; gsrc is per-lane, ldst is wave-uniform
#define GLL16(gsrc, ldst)                                                   \
    __builtin_amdgcn_global_load_lds(                                       \
        (const __attribute__((address_space(1))) unsigned int*)(gsrc),      \
        (__attribute__((address_space(3))) unsigned int*)(ldst), 16, 0, 0)

// ---------------------------------------------------------------------------
// Kernel 1: per-block partials of S = F^T F and colsum(F).
// NEW: half-tile (32 rows = 8 KB) staged into wave-private LDS via
// global_load_lds DMA (8 x 1024B, coalesced, no VGPR roundtrip); the strided
// column reads become ds_read_b32 (4-way bank alias, latency-hidden).
// Fragment (g,i,jt,kk,r) -> F element mapping identical to the R2-proven
// kernel, so the Gram/MFMA numerics are unchanged.
// ---------------------------------------------------------------------------
__global__ __launch_bounds__(256) void k1_stats(const float* __restrict__ F,
                                                float* __restrict__ Sp,
                                                float* __restrict__ Cp) {
    const int tid = threadIdx.x;
    const int wid = tid >> 6;
    const int lane = tid & 63;
    const int g = lane >> 4;
    const int i = lane & 15;
    const int gw = blockIdx.x * 4 + wid;

    __shared__ float tileL[4][2048];  // 32 KB: 8 KB wave-private half-tile

    f32x4 acc[4][4];
#pragma unroll
    for (int a = 0; a < 4; ++a)
#pragma unroll
        for (int b = 0; b < 4; ++b)
            acc[a][b] = (f32x4){0.f, 0.f, 0.f, 0.f};
    float colp[4] = {0.f, 0.f, 0.f, 0.f};

    for (int tile = gw; tile < TILES; tile += K1_WAVES) {
#pragma unroll
        for (int kk = 0; kk < 2; ++kk) {
            // ---- stage rows [kk*32, kk*32+32) of this 64x64 tile ----
            const float* src = F + (size_t)tile * 4096 + kk * 2048 + lane * 4;
#pragma unroll
            for (int it = 0; it < 8; ++it)
                GLL16(src + it * 256, &tileL[wid][it * 256]);
            __builtin_amdgcn_sched_barrier(0);
            asm volatile("s_waitcnt vmcnt(0)" ::: "memory");
            __builtin_amdgcn_sched_barrier(0);

            // ---- fragments + colsum from LDS (same mapping as before) ----
            short8v frag[4];
#pragma unroll
            for (int jt = 0; jt < 4; ++jt) {
                float cs = 0.f;
                short8v fr;
#pragma unroll
                for (int r = 0; r < 8; ++r) {
                    float v = tileL[wid][(g * 8 + r) * 64 + jt * 16 + i];
                    cs += v;
                    fr[r] = bf16_of(v);
                }
                frag[jt] = fr;
                colp[jt] += cs;
            }
#pragma unroll
            for (int it = 0; it < 4; ++it)
#pragma unroll
                for (int jt = 0; jt < 4; ++jt)
                    acc[it][jt] = __builtin_amdgcn_mfma_f32_16x16x32_bf16(
                        frag[it], frag[jt], acc[it][jt], 0, 0, 0);
        }
    }

    // colsum: combine the 4 lane-groups holding the same column
#pragma unroll
    for (int jt = 0; jt < 4; ++jt) {
        colp[jt] += __shfl_xor(colp[jt], 16);
        colp[jt] += __shfl_xor(colp[jt], 32);
    }
    if (lane < 16) {
#pragma unroll
        for (int jt = 0; jt < 4; ++jt)
            Cp[gw * 64 + jt * 16 + lane] = colp[jt];
    }

    // block-level reduction of the 4 waves' S partials (reuse tileL as sS)
    float* sS = &tileL[0][0];  // 4096 floats needed, 8192 available
    __syncthreads();           // all waves done with their tileL regions
    for (int w = 0; w < 4; ++w) {
        if (wid == w) {
#pragma unroll
            for (int it = 0; it < 4; ++it)
#pragma unroll
                for (int jt = 0; jt < 4; ++jt)
#pragma unroll
                    for (int r = 0; r < 4; ++r) {
                        // C/D layout: col = lane&15, row = (lane>>4)*4 + reg
                        int idx = (it * 16 + g * 4 + r) * 64 + jt * 16 + i;
                        if (w == 0) sS[idx] = acc[it][jt][r];
                        else        sS[idx] += acc[it][jt][r];
                    }
        }
        __syncthreads();
    }
    float4* dst = (float4*)(Sp + (size_t)blockIdx.x * 4096);
    const float4* src4 = (const float4*)sS;
#pragma unroll
    for (int q = 0; q < 4; ++q)
        dst[q * 256 + tid] = src4[q * 256 + tid];
}

// ---------------------------------------------------------------------------
// Reduce stage A: shallow partial reduction (R7 shapes).
// ---------------------------------------------------------------------------
__global__ __launch_bounds__(256) void kRedA(const float* __restrict__ Sp,
                                             const float* __restrict__ Cp,
                                             float* __restrict__ Tp,
                                             float* __restrict__ Tcp) {
    int t = blockIdx.x * 256 + threadIdx.x;
    if (t < SP_CHUNKS * 4096) {
        int o = t & 4095;
        int c = t >> 12;
        float s = 0.f;
#pragma unroll 10
        for (int b = 0; b < SP_DEPTH; ++b)
            s += Sp[(size_t)(c * SP_DEPTH + b) * 4096 + o];
        Tp[t] = s;
    } else if (t < SP_CHUNKS * 4096 + CP_CHUNKS * 64) {
        int u = t - SP_CHUNKS * 4096;
        int col = u & 63;
        int c = u >> 6;
        float s = 0.f;
#pragma unroll 10
        for (int w = 0; w < CP_DEPTH; ++w)
            s += Cp[(c * CP_DEPTH + w) * 64 + col];
        Tcp[u] = s;
    }
}

// Reduce stage B: chunk partials -> S, colsum
__global__ __launch_bounds__(256) void kRedB(const float* __restrict__ Tp,
                                             const float* __restrict__ Tcp,
                                             float* __restrict__ S,
                                             float* __restrict__ colsum) {
    int t = blockIdx.x * 256 + threadIdx.x;
    if (t < 4096) {
        float s = 0.f;
#pragma unroll
        for (int c = 0; c < SP_CHUNKS; ++c) s += Tp[c * 4096 + t];
        S[t] = s;
    } else if (t < 4160) {
        int col = t - 4096;
        float s = 0.f;
#pragma unroll
        for (int c = 0; c < CP_CHUNKS; ++c) s += Tcp[c * 64 + col];
        colsum[col] = s;
    }
}

// ---------------------------------------------------------------------------
// BN affine constants: mu_d = (W_d . colsum)/M, E[x^2]_d = (W_d^T S W_d)/M
// ---------------------------------------------------------------------------
__global__ __launch_bounds__(64) void k1_scales(const float* __restrict__ S,
                                                const float* __restrict__ colsum,
                                                const float* __restrict__ W,
                                                const float* __restrict__ gamma,
                                                const float* __restrict__ beta,
                                                float* __restrict__ scale,
                                                float* __restrict__ shift) {
    int d = blockIdx.x;
    int tid = threadIdx.x;
    __shared__ float w[64];
    w[tid] = W[d * 64 + tid];
    __syncthreads();
    float wi = w[tid];
    float rowdot = 0.f;
#pragma unroll
    for (int j = 0; j < 64; ++j) rowdot += S[tid * 64 + j] * w[j];
    float p = wi * rowdot;
    float mup = wi * colsum[tid];
    for (int k = 1; k <= 32; k <<= 1) {
        p += __shfl_xor(p, k);
        mup += __shfl_xor(mup, k);
    }
    if (tid == 0) {
        const float invM = 1.f / (float)M_ROWS;
        float mu = mup * invM;
        float ex2 = p * invM;
        float var = ex2 - mu * mu;
        float rs = rsqrtf(var + BN_EPS);
        float sc = gamma[d] * rs;
        scale[d] = sc;
        shift[d] = beta[d] - mu * sc;
    }
}

// ---------------------------------------------------------------------------
// Kernel 2 (exact R2 structure, best-measured): fused GEMM (bf16 MFMA) +
// BN affine + ReLU + geo-weighted masked mean-pool.  One wave per 4 points.
// ---------------------------------------------------------------------------
__global__ __launch_bounds__(256) void k2_main(const float* __restrict__ F,
                                               const float* __restrict__ coords,
                                               const float* __restrict__ centers,
                                               const int* __restrict__ mask,
                                               const float* __restrict__ W,
                                               const float* __restrict__ scale,
                                               const float* __restrict__ shift,
                                               float* __restrict__ out) {
    const int tid = threadIdx.x;
    const int wid = tid >> 6;
    const int lane = tid & 63;
    const int g = lane >> 4;
    const int i = lane & 15;
    const int n_base = (blockIdx.x * 4 + wid) * 4;

    short8v b[8][2];
#pragma unroll
    for (int t = 0; t < 8; ++t)
#pragma unroll
        for (int kk = 0; kk < 2; ++kk) {
            const float* wp = W + (t * 16 + i) * 64 + kk * 32 + g * 8;
            short8v fr;
#pragma unroll
            for (int r = 0; r < 8; ++r) fr[r] = bf16_of(wp[r]);
            b[t][kk] = fr;
        }
    float sc[8], sh[8];
#pragma unroll
    for (int t = 0; t < 8; ++t) {
        sc[t] = scale[t * 16 + i];
        sh[t] = shift[t * 16 + i];
    }

    __shared__ float geoM[4][32][4];
    const f32x4 Z = {0.f, 0.f, 0.f, 0.f};

    for (int it = 0; it < 4; ++it) {
        const int n = n_base + it;

        short8v a[2][2];
#pragma unroll
        for (int mt = 0; mt < 2; ++mt)
#pragma unroll
            for (int kk = 0; kk < 2; ++kk) {
                const float* fp =
                    F + ((size_t)n * NSAMP + mt * 16 + i) * 64 + kk * 32 + g * 8;
                short8v fr;
#pragma unroll
                for (int r = 0; r < 8; ++r) fr[r] = bf16_of(fp[r]);
                a[mt][kk] = fr;
            }

        float m = 0.f;
        if (lane < 32) {
            const int s = lane;
            const float* cp = coords + ((size_t)n * NSAMP + s) * 3;
            float r0 = cp[0] - centers[n * 4 + 1];
            float r1 = cp[1] - centers[n * 4 + 2];
            float r2 = cp[2] - centers[n * 4 + 3];
            float dist = r0 * r0 + r1 * r1 + r2 * r2;
            m = (float)mask[n * NSAMP + s];
            float4 gm = make_float4(r0 * 10.f * m, r1 * 10.f * m,
                                    r2 * 5.f * m, dist * (1.f / 0.06f) * m);
            *(float4*)&geoM[wid][s][0] = gm;
        }
        float den = m;
        for (int k = 1; k <= 32; k <<= 1) den += __shfl_xor(den, k);
        float inv_den = 1.f / fmaxf(den, 1.f);

        __builtin_amdgcn_sched_barrier(0x7F);

        float gv[2][4];
        const int j0 = i & 3;
#pragma unroll
        for (int mt = 0; mt < 2; ++mt)
#pragma unroll
            for (int r = 0; r < 4; ++r)
                gv[mt][r] = geoM[wid][mt * 16 + g * 4 + r][j0];

#pragma unroll
        for (int t = 0; t < 8; ++t) {
            float nump = 0.f;
#pragma unroll
            for (int mt = 0; mt < 2; ++mt) {
                f32x4 acc = __builtin_amdgcn_mfma_f32_16x16x32_bf16(
                    a[mt][0], b[t][0], Z, 0, 0, 0);
                acc = __builtin_amdgcn_mfma_f32_16x16x32_bf16(
                    a[mt][1], b[t][1], acc, 0, 0, 0);
#pragma unroll
                for (int r = 0; r < 4; ++r) {
                    float v = fmaf(acc[r], sc[t], sh[t]);
                    v = fmaxf(v, 0.f);
                    nump = fmaf(v, gv[mt][r], nump);
                }
            }
            nump += __shfl_xor(nump, 16);
            nump += __shfl_xor(nump, 32);
            if (lane < 16)
                out[(size_t)n * COUT + t * 16 + lane] = nump * inv_den;
        }
    }
}

// ---------------------------------------------------------------------------
extern "C" void kernel_launch(void* const* d_in, const int* in_sizes, int n_in,
                              void* d_out, int out_size, void* d_ws, size_t ws_size,
                              hipStream_t stream) {
    const float* F = (const float*)d_in[0];
    const float* coords = (const float*)d_in[1];
    const float* centers = (const float*)d_in[2];
    const int* mask = (const int*)d_in[3];
    const float* W = (const float*)d_in[4];
    const float* gamma = (const float*)d_in[5];
    const float* beta = (const float*)d_in[6];
    float* out = (float*)d_out;

    float* wsf = (float*)d_ws;
    float* scale = wsf;                          // 128
    float* shift = wsf + 128;                    // 128
    float* S = wsf + 256;                        // 4096
    float* colsum = wsf + 4352;                  // 64
    float* Tp = wsf + 4416;                      // 102400
    float* Tcp = Tp + SP_CHUNKS * 4096;          // 3200
    float* Sp = Tcp + CP_CHUNKS * 64;            // 1250*4096
    float* Cp = Sp + (size_t)K1_BLOCKS * 4096;   // 5000*64

    k1_stats<<<K1_BLOCKS, 256, 0, stream>>>(F, Sp, Cp);
    kRedA<<<413, 256, 0, stream>>>(Sp, Cp, Tp, Tcp);
    kRedB<<<17, 256, 0, stream>>>(Tp, Tcp, S, colsum);
    k1_scales<<<COUT, 64, 0, stream>>>(S, colsum, W, gamma, beta, scale, shift);
    k2_main<<<1250, 256, 0, stream>>>(F, coords, centers, mask, W, scale, shift, out);
}